// Round 11
// baseline (675.204 us; speedup 1.0000x reference)
//
#include <hip/hip_runtime.h>
#include <hip/hip_bf16.h>
#include <math.h>

#define DEV static __device__ __forceinline__

typedef __attribute__((ext_vector_type(8))) short short8;
typedef __attribute__((ext_vector_type(4))) float floatx4;

DEV float bf2f(const __hip_bfloat16 v) { return __bfloat162float(v); }
DEV float bfu2f(unsigned short u) { return __uint_as_float((unsigned)u << 16); }

DEV unsigned short f2bf(float v) {   // RNE f32 -> bf16 bits
    unsigned int b = __float_as_uint(v);
    unsigned int r = (b + 0x7FFFu + ((b >> 16) & 1u)) >> 16;
    return (unsigned short)r;
}

DEV float mishf(float x) {
    float sp = fmaxf(x, 0.0f) + __logf(1.0f + __expf(-fabsf(x)));
    float t = __expf(-2.0f * sp);
    return __fdividef(x * (1.0f - t), 1.0f + t);
}

// wait until at most N VMEM loads outstanding (gfx9 encoding; lgkm/exp ignored)
template<int N> DEV void s_wait_vm() {
    constexpr unsigned e = (unsigned)(N & 15) | (((unsigned)N >> 4) << 14)
                         | (7u << 4) | (15u << 8);
    __builtin_amdgcn_s_waitcnt(e);
}

#define N_T 32
struct Tab {
    const void* src[N_T];
    long long   dstoff[N_T];
    int         n[N_T];
    int         isw[N_T];   // 1 = conv weight -> bf16 WB region (frag layout)
    int         cin[N_T];
    int         kk[N_T];
    int         bs[N_T];                 // block-prefix (static sizes)
    unsigned long long mckk[N_T];        // magic: ceil(2^39 / (cin*kk))
    unsigned long long mkk[N_T];         // magic: ceil(2^39 / kk)
};

// ---------------- per-array dtype detection ----------------
__global__ __launch_bounds__(256) void k_detect(Tab t, int* __restrict__ flags) {
    int i = blockIdx.x;
    int n = t.n[i];
    int m = n < 16384 ? n : 16384;
    const unsigned short* p = (const unsigned short*)t.src[i];
    __shared__ int sInf, sExt, sZero;
    if (threadIdx.x == 0) { sInf = 0; sExt = 0; sZero = 0; }
    __syncthreads();
    int cInf = 0, cExt = 0, cZero = 0;
    for (int j = threadIdx.x; j < m; j += 256) {
        unsigned short h = p[j];
        if ((h & 0x7F80) == 0x7F80) cInf++;
        if ((j & 1) == 0) {
            if (h == 0) cZero++;
            else { int e = (h >> 7) & 0xFF; if (e < 56 || e > 184) cExt++; }
        }
    }
    if (cInf)  atomicAdd(&sInf, cInf);
    if (cExt)  atomicAdd(&sExt, cExt);
    if (cZero) atomicAdd(&sZero, cZero);
    __syncthreads();
    if (threadIdx.x == 0) {
        int nEven = (m + 1) >> 1;
        flags[i] = (sInf > 0 || sExt > 0 || (nEven > 0 && sZero == nEven)) ? 2 : 0;
    }
}

__global__ void k_flag_final(Tab t, int* __restrict__ flags, int xi,
                             float* __restrict__ zp) {
    if (blockIdx.x == 0 && threadIdx.x < 16) zp[threadIdx.x] = 0.0f;
    if (threadIdx.x == 0 && blockIdx.x == 0) {
        int xf = (flags[xi] == 2) ? 1 : 0;
        for (int i = 0; i < N_T; ++i) {
            int f;
            if (flags[i] == 2)       f = 1;
            else if (t.n[i] >= 256)  f = 0;
            else                     f = xf;
            flags[i] = f;            // 1 = f32, 0 = bf16
        }
    }
}

// convert: conv weights -> bf16 WB in MFMA-fragment order. Block->entry via
// static block-prefix (scalar scan); divisions via host-precomputed magic
// multiply ((j*M)>>39, exact for j<2^22, D<=8192).
__global__ __launch_bounds__(256) void k_convert(
        Tab t, float* __restrict__ pf, unsigned short* __restrict__ wb,
        const int* __restrict__ flags) {
    int bx = blockIdx.x;
    int i = 0;
    #pragma unroll 1
    while (i + 1 < N_T && bx >= t.bs[i + 1]) ++i;
    int j = (bx - t.bs[i]) * 256 + threadIdx.x;
    if (j >= t.n[i]) return;
    float v = flags[i] ? ((const float*)t.src[i])[j]
                       : bf2f(((const __hip_bfloat16*)t.src[i])[j]);
    if (t.isw[i]) {
        int kk = t.kk[i], cin = t.cin[i];
        int ckk = cin * kk;
        unsigned co = (unsigned)(((unsigned long long)(unsigned)j
                                  * t.mckk[i]) >> 39);
        int rem = j - (int)co * ckk;
        unsigned ci = (unsigned)(((unsigned long long)(unsigned)rem
                                  * t.mkk[i]) >> 39);
        int tt = rem - (int)ci * kk;
        int cb = (int)co >> 4, m = (int)co & 15;
        int ch = (int)ci >> 5, q = ((int)ci >> 3) & 3, jj = (int)ci & 7;
        int nc = cin >> 5;
        size_t dst = (((size_t)(cb * kk + tt) * nc + ch) << 9)
                   + (size_t)((q << 4) + m) * 8 + jj;
        wb[t.dstoff[i] + dst] = f2bf(v);
    } else {
        pf[t.dstoff[i] + j] = v;
    }
}

// ------- dynamic per-sample conv (k=4, pad=1) + mish -> NHWC bf16 -----------
__global__ __launch_bounds__(256) void k_dynconv_mish(
        const float* __restrict__ x, const float* __restrict__ w,
        unsigned short* __restrict__ out) {
    const int HO = 255, WO = 255, H = 256, W = 256;
    int p = blockIdx.x * 256 + threadIdx.x;
    if (p >= HO * WO) return;
    int b = blockIdx.y;
    int yo = p / WO, xo = p - yo * WO;
    const float* xp = x + b * H * W;

    float xv[16];
    #pragma unroll
    for (int ky = 0; ky < 4; ++ky) {
        int iy = yo + ky - 1;
        bool yok = (unsigned)iy < (unsigned)H;
        #pragma unroll
        for (int kx = 0; kx < 4; ++kx) {
            int ix = xo + kx - 1;
            xv[ky * 4 + kx] = (yok && (unsigned)ix < (unsigned)W)
                              ? xp[iy * W + ix] : 0.0f;
        }
    }

    const float* wb = w + (b << 9);
    unsigned int ow[16];
    #pragma unroll
    for (int c2 = 0; c2 < 16; ++c2) {
        const float* w0 = wb + (c2 << 5);
        const float* w1 = w0 + 16;
        float a0 = 0.f, a1 = 0.f;
        #pragma unroll
        for (int k = 0; k < 16; ++k) {
            a0 = fmaf(xv[k], w0[k], a0);
            a1 = fmaf(xv[k], w1[k], a1);
        }
        ow[c2] = (unsigned)f2bf(mishf(a0)) | ((unsigned)f2bf(mishf(a1)) << 16);
    }

    unsigned short* op = out + ((size_t)(b * HO * WO) + p) * 32;
    uint4 v;
    v.x = ow[0];  v.y = ow[1];  v.z = ow[2];  v.w = ow[3];
    *(uint4*)(op +  0) = v;
    v.x = ow[4];  v.y = ow[5];  v.z = ow[6];  v.w = ow[7];
    *(uint4*)(op +  8) = v;
    v.x = ow[8];  v.y = ow[9];  v.z = ow[10]; v.w = ow[11];
    *(uint4*)(op + 16) = v;
    v.x = ow[12]; v.y = ow[13]; v.z = ow[14]; v.w = ow[15];
    *(uint4*)(op + 24) = v;
}

// ============ halo-staged NHWC direct-conv MFMA (bf16 in/out, f32 acc) =======
// Block = 256 threads = 4 waves arranged WPX (px) x WCO (co).
// T4 counted-vmcnt pipeline per 32-ci chunk (see R9); KS==3 row-major B reads
// (18 ds_read instead of 36).
// T2 LDS XOR-swizzle (R11): the B read at byte loc*64 + qd*16 had bank =
// (loc&1)*16 + qd*4 -> 8-way conflict across the 16 pixel-lanes. Swizzle:
// slot (loc, s) stores ci-group qd = s ^ ((loc>>1)&3). Write side stays a
// LINEAR global_load_lds dest (required) with the inverse permutation applied
// to the global SOURCE (c8 per pass); read side XORs the same bits. 16
// consecutive loc now cover all 32 banks (2-way residual = free).
template<int KS, int WPX, int WCO, int CO_FR>
__global__ __launch_bounds__(256) void k_conv2(
        const unsigned short* __restrict__ s0, int C0,
        const unsigned short* __restrict__ s1, int C1,
        const unsigned short* __restrict__ wgt,
        const float* __restrict__ bias,
        unsigned short* __restrict__ out,
        int Hin, int Win, int Hout, int Wout, int Co,
        const float* __restrict__ zpad) {
    constexpr int PAD = KS - 2;               // 3->1, 4->2
    constexpr int KK = KS * KS;
    constexpr int TY = WPX * 4;
    constexpr int HWd = 16 + KS - 1;
    constexpr int HHd = TY + KS - 1;
    constexpr int NLOC = HWd * HHd;
    constexpr int NLD = NLOC * 4;             // 16B-loads per chunk
    constexpr int NPASS = (NLD + 255) / 256;
    constexpr int HALF = NPASS * 2048;        // shorts per buffer half
    constexpr int NAV = (KS == 3) ? KK * CO_FR : 0;
    static_assert(2 * HALF * 2 <= 65536, "LDS overflow");
    static_assert(WPX * WCO == 4, "4 waves");
    static_assert(NAV + NPASS <= 63, "vmcnt range");
    __shared__ __align__(16) unsigned short lds[2 * HALF];

    const int tid = threadIdx.x, lane = tid & 63, wv = tid >> 6;
    const int wr = wv / WCO, wc = wv % WCO;
    const int xn = lane & 15, qd = lane >> 4;
    const int C = C0 + C1, NC = C >> 5;
    const int NC0 = C0 >> 5;

    const int txc = Wout >> 4, tyc = Hout / TY;
    const int tpb = txc * tyc;
    const int b = blockIdx.x / tpb;
    int rem = blockIdx.x - b * tpb;
    const int tyi = rem / txc, txi = rem - tyi * txc;
    const int y0 = tyi * TY, x0 = txi << 4;
    const int cobase = blockIdx.y * (WCO * CO_FR * 16);
    const int cob16_0 = (cobase >> 4) + wc * CO_FR;

    const unsigned short* sb0 = s0 + (size_t)b * Hin * Win * C0;
    const unsigned short* sb1 = s1 ? s1 + (size_t)b * Hin * Win * C1 : s0;

    // swizzled LDS byte->short offset for pixel-slot t, ci-group qd
    auto swz = [&](int t) { return t * 32 + (((qd ^ (t >> 1)) & 3) << 3); };

    floatx4 acc[4][CO_FR];
    #pragma unroll
    for (int p = 0; p < 4; ++p)
        #pragma unroll
        for (int q = 0; q < CO_FR; ++q)
            acc[p][q] = (floatx4){0.f, 0.f, 0.f, 0.f};

    // --- hoisted staging state (chunk-independent parts) ---
    int srow[NPASS];
    int sinc[NPASS];                          // 32 if lane stages real data
    int c8s[NPASS];                           // inverse-swizzled ci-group
    #pragma unroll
    for (int p_ = 0; p_ < NPASS; ++p_) {
        int i_ = p_ * 256 + tid;
        int loc = i_ >> 2;
        int hy = loc / HWd, hx = loc - hy * HWd;
        int iy = y0 + hy - PAD, ix = x0 + hx - PAD;
        bool ok = (i_ < NLD) && ((unsigned)iy < (unsigned)Hin)
                             && ((unsigned)ix < (unsigned)Win);
        srow[p_] = iy * Win + ix;
        sinc[p_] = ok ? 32 : 0;
        c8s[p_] = (((i_ & 3) ^ ((i_ >> 3) & 3))) << 3;
    }
    const unsigned short* sptr[NPASS];
    auto initp = [&](const unsigned short* srcp, int Cs) {
        #pragma unroll
        for (int p_ = 0; p_ < NPASS; ++p_)
            sptr[p_] = sinc[p_] ? srcp + (size_t)srow[p_] * Cs + c8s[p_]
                                : (const unsigned short*)zpad;
    };
    int scnt = 0;
    auto stage_next = [&](int h_) {
        if (s1 && scnt == NC0) initp(sb1, C1);
        #pragma unroll
        for (int p_ = 0; p_ < NPASS; ++p_) {
            __builtin_amdgcn_global_load_lds(
                (const unsigned int*)sptr[p_],
                (unsigned int*)&lds[h_ * HALF + (p_ * 256 + wv * 64) * 8],
                16, 0, 0);
            sptr[p_] += sinc[p_];
        }
        ++scnt;
    };

    initp(sb0, C0);
    stage_next(0);
    for (int ci_ = 0; ci_ < NC; ++ci_) {
        const int h = ci_ & 1;
        const size_t wof = ((size_t)cob16_0 * KK * NC + ci_) * 512 + lane * 8;
        // 1) A-fragment prefetch into regs, issued BEFORE staging so the
        //    compiler's av-consume waits exclude the fresh staging loads.
        short8 avr[KK][CO_FR];
        if constexpr (KS == 3) {
            #pragma unroll
            for (int tap = 0; tap < KK; ++tap)
                #pragma unroll
                for (int q = 0; q < CO_FR; ++q)
                    avr[tap][q] = *(const short8*)(wgt + wof
                                    + (size_t)(q * KK + tap) * NC * 512);
            __builtin_amdgcn_sched_barrier(0);
        }
        // 2) issue next-chunk staging (stays in flight across the barrier)
        if (ci_ + 1 < NC) stage_next(h ^ 1);
        __builtin_amdgcn_sched_barrier(0);
        // 3) counted wait: everything older than {avr, next staging} retired
        //    => this chunk's staging landed (in-order vmcnt retirement)
        if (ci_ + 1 < NC) s_wait_vm<NAV + NPASS>();
        else              s_wait_vm<NAV>();
        __builtin_amdgcn_s_barrier();
        __builtin_amdgcn_sched_barrier(0);
        // 4) compute this chunk from LDS + avr
        const unsigned short* base = &lds[h * HALF];
        if constexpr (KS == 3) {
            // row-major: each of the 6 halo rows read once (3 dx frags)
            #pragma unroll
            for (int r = 0; r < 6; ++r) {
                short8 bv[3];
                #pragma unroll
                for (int dx = 0; dx < 3; ++dx) {
                    int t = (4 * wr + r) * HWd + xn + dx;
                    bv[dx] = *(const short8*)&base[swz(t)];
                }
                #pragma unroll
                for (int dy = 0; dy < 3; ++dy) {
                    const int p = r - dy;
                    if (p >= 0 && p < 4) {
                        #pragma unroll
                        for (int dx = 0; dx < 3; ++dx) {
                            const int tap = dy * 3 + dx;
                            #pragma unroll
                            for (int q = 0; q < CO_FR; ++q)
                                acc[p][q] =
                                    __builtin_amdgcn_mfma_f32_16x16x32_bf16(
                                        avr[tap][q], bv[dx], acc[p][q],
                                        0, 0, 0);
                        }
                    }
                }
            }
        } else {
            #pragma unroll
            for (int dy = 0; dy < KS; ++dy) {
                #pragma unroll
                for (int dx = 0; dx < KS; ++dx) {
                    const int tap = dy * KS + dx;
                    short8 av[CO_FR];
                    #pragma unroll
                    for (int q = 0; q < CO_FR; ++q)
                        av[q] = *(const short8*)(wgt + wof
                                  + (size_t)(q * KK + tap) * NC * 512);
                    #pragma unroll
                    for (int p = 0; p < 4; ++p) {
                        int t = (4 * wr + p + dy) * HWd + xn + dx;
                        short8 bv = *(const short8*)&base[swz(t)];
                        #pragma unroll
                        for (int q = 0; q < CO_FR; ++q)
                            acc[p][q] = __builtin_amdgcn_mfma_f32_16x16x32_bf16(
                                av[q], bv, acc[p][q], 0, 0, 0);
                    }
                }
            }
        }
        __builtin_amdgcn_sched_barrier(0);
        __builtin_amdgcn_s_barrier();     // WAR: all waves done reading buf[h]
        __builtin_amdgcn_sched_barrier(0);
    }

    // epilogue: bias + mish -> NHWC bf16, 4 consecutive co per lane
    #pragma unroll
    for (int p = 0; p < 4; ++p) {
        const int y = y0 + 4 * wr + p;
        unsigned short* ob = out + (((size_t)b * Hout + y) * Wout + x0 + xn) * Co;
        #pragma unroll
        for (int q = 0; q < CO_FR; ++q) {
            const int co = cobase + (wc * CO_FR + q) * 16 + qd * 4;
            ushort4 o;
            o.x = f2bf(mishf(acc[p][q][0] + bias[co + 0]));
            o.y = f2bf(mishf(acc[p][q][1] + bias[co + 1]));
            o.z = f2bf(mishf(acc[p][q][2] + bias[co + 2]));
            o.w = f2bf(mishf(acc[p][q][3] + bias[co + 3]));
            *(ushort4*)(ob + co) = o;
        }
    }
}

// ------- 2x2 maxpool stride 2 (NHWC bf16, square pow2), 8 ch/thread --------
__global__ __launch_bounds__(256) void k_maxpool(
        const unsigned short* __restrict__ in, unsigned short* __restrict__ out,
        int lgWin, int lgC, int total8) {
    int idx = blockIdx.x * 256 + threadIdx.x;
    if (idx >= total8) return;
    int Wo = 1 << (lgWin - 1);
    int vc = idx & ((1 << (lgC - 3)) - 1); int t = idx >> (lgC - 3);
    int xo = t & (Wo - 1); t >>= (lgWin - 1);
    int yo = t & (Wo - 1); int b = t >> (lgWin - 1);
    size_t base = (((((size_t)(b << lgWin) + 2 * yo) << lgWin) + 2 * xo) << lgC)
                + ((size_t)vc << 3);
    size_t dc = (size_t)1 << lgC, dr = (size_t)1 << (lgWin + lgC);
    short8 v0 = *(const short8*)&in[base];
    short8 v1 = *(const short8*)&in[base + dc];
    short8 v2 = *(const short8*)&in[base + dr];
    short8 v3 = *(const short8*)&in[base + dr + dc];
    short8 o;
    #pragma unroll
    for (int j = 0; j < 8; ++j) {
        float m = fmaxf(fmaxf(bfu2f((unsigned short)v0[j]),
                              bfu2f((unsigned short)v1[j])),
                        fmaxf(bfu2f((unsigned short)v2[j]),
                              bfu2f((unsigned short)v3[j])));
        o[j] = (short)f2bf(m);
    }
    *(short8*)&out[(size_t)idx * 8] = o;
}

// ---------------- batchnorm (batch stats) on NHWC (4,32,32,512) bf16 --------
__global__ __launch_bounds__(256) void k_bn_reduce(
        const unsigned short* __restrict__ in, float* __restrict__ stats) {
    __shared__ float ls[4], ls2[4];
    int c = blockIdx.x;
    int tid = threadIdx.x;
    float s = 0.f, s2 = 0.f;
    for (int i = tid; i < 4096; i += 256) {
        float v = bfu2f(in[(size_t)i * 512 + c]);
        s += v; s2 += v * v;
    }
    #pragma unroll
    for (int off = 32; off; off >>= 1) {
        s  += __shfl_down(s, off, 64);
        s2 += __shfl_down(s2, off, 64);
    }
    if ((tid & 63) == 0) { ls[tid >> 6] = s; ls2[tid >> 6] = s2; }
    __syncthreads();
    if (tid == 0) {
        s  = ls[0] + ls[1] + ls[2] + ls[3];
        s2 = ls2[0] + ls2[1] + ls2[2] + ls2[3];
        float mean = s * (1.f / 4096.f);
        float var  = fmaxf(s2 * (1.f / 4096.f) - mean * mean, 0.f);
        stats[c]       = mean;
        stats[512 + c] = rsqrtf(var + 1e-5f);
    }
}

// bn apply, 8 ch/thread (short8)
__global__ __launch_bounds__(256) void k_bn_apply(
        unsigned short* __restrict__ data, const float* __restrict__ stats,
        const float* __restrict__ g, const float* __restrict__ be, int total8) {
    int idx = blockIdx.x * 256 + threadIdx.x;
    if (idx >= total8) return;
    int c0 = (idx & 63) << 3;
    short8 v = *(const short8*)&data[(size_t)idx * 8];
    short8 o;
    #pragma unroll
    for (int j = 0; j < 8; ++j) {
        int c = c0 + j;
        float x = bfu2f((unsigned short)v[j]);
        o[j] = (short)f2bf(g[c] * (x - stats[c]) * stats[512 + c] + be[c]);
    }
    *(short8*)&data[(size_t)idx * 8] = o;
}

// ---- bilinear x2 upsample, align_corners=True, NHWC bf16, 8 ch/thread ------
__global__ __launch_bounds__(256) void k_up2(
        const unsigned short* __restrict__ in, unsigned short* __restrict__ out,
        int lgW, int lgC, int total8) {
    int idx = blockIdx.x * 256 + threadIdx.x;
    if (idx >= total8) return;
    int H = 1 << lgW;
    int vc = idx & ((1 << (lgC - 3)) - 1); int t = idx >> (lgC - 3);
    int xo = t & (2 * H - 1); t >>= (lgW + 1);
    int yo = t & (2 * H - 1); int b = t >> (lgW + 1);
    float sc = (float)(H - 1) / (float)(2 * H - 1);
    float sy = yo * sc, sx = xo * sc;
    int y0 = (int)sy; int y1 = min(y0 + 1, H - 1); float fy = sy - (float)y0;
    int x0 = (int)sx; int x1 = min(x0 + 1, H - 1); float fx = sx - (float)x0;
    size_t bb = (size_t)b << (2 * lgW);
    size_t c = (size_t)vc << 3;
    size_t i00 = (((bb + ((size_t)y0 << lgW) + x0)) << lgC) + c;
    size_t i01 = (((bb + ((size_t)y0 << lgW) + x1)) << lgC) + c;
    size_t i10 = (((bb + ((size_t)y1 << lgW) + x0)) << lgC) + c;
    size_t i11 = (((bb + ((size_t)y1 << lgW) + x1)) << lgC) + c;
    short8 a00 = *(const short8*)&in[i00];
    short8 a01 = *(const short8*)&in[i01];
    short8 a10 = *(const short8*)&in[i10];
    short8 a11 = *(const short8*)&in[i11];
    short8 o;
    #pragma unroll
    for (int j = 0; j < 8; ++j) {
        float a  = bfu2f((unsigned short)a00[j]) * (1.f - fx)
                 + bfu2f((unsigned short)a01[j]) * fx;
        float b2 = bfu2f((unsigned short)a10[j]) * (1.f - fx)
                 + bfu2f((unsigned short)a11[j]) * fx;
        o[j] = (short)f2bf(a * (1.f - fy) + b2 * fy);
    }
    *(short8*)&out[(size_t)idx * 8] = o;
}

// ---------------- final 1x1 conv, NHWC(4,256,256,32) bf16 -> f32 ------------
__global__ __launch_bounds__(256) void k_final1x1(
        const unsigned short* __restrict__ in, const float* __restrict__ wl,
        const float* __restrict__ bl, float* __restrict__ out) {
    int idx = blockIdx.x * 256 + threadIdx.x;
    if (idx >= 4 * 256 * 256) return;
    const unsigned short* p = in + (size_t)idx * 32;
    short8 r0 = *(const short8*)&p[0];
    short8 r1 = *(const short8*)&p[8];
    short8 r2 = *(const short8*)&p[16];
    short8 r3 = *(const short8*)&p[24];
    float acc = bl[0];
    #pragma unroll
    for (int j = 0; j < 8; ++j) {
        acc = fmaf(bfu2f((unsigned short)r0[j]), wl[j],      acc);
        acc = fmaf(bfu2f((unsigned short)r1[j]), wl[j + 8],  acc);
        acc = fmaf(bfu2f((unsigned short)r2[j]), wl[j + 16], acc);
        acc = fmaf(bfu2f((unsigned short)r3[j]), wl[j + 24], acc);
    }
    out[idx] = acc;
}

static inline int nblk(long long n) { return (int)((n + 255) / 256); }

extern "C" void kernel_launch(void* const* d_in, const int* in_sizes, int n_in,
                              void* d_out, int out_size, void* d_ws, size_t ws_size,
                              hipStream_t stream) {
    static const int EXP_SZ[N_T] = {
        262144, 2048, 16384, 32, 36864, 128, 147456, 128,
        294912, 256, 589824, 256, 1179648, 512, 2359296, 512,
        512, 512, 1769472, 256, 589824, 256, 442368, 128,
        147456, 128, 46080, 32, 9216, 32, 32, 1 };
    static const int ISW[N_T] = {
        0,0,1,0, 1,0,1,0, 1,0,1,0, 1,0,1,0,
        0,0, 1,0,1,0, 1,0,1,0, 1,0,1,0, 0,0 };
    static const int CIN[N_T] = {
        0,0,32,0, 32,0,128,0, 128,0,256,0, 256,0,512,0,
        0,0, 768,0,256,0, 384,0,128,0, 160,0,32,0, 0,0 };
    static const int KKA[N_T] = {
        0,0,16,0, 9,0,9,0, 9,0,9,0, 9,0,9,0,
        0,0, 9,0,9,0, 9,0,9,0, 9,0,9,0, 0,0 };
    int o = -1;
    for (int s = 0; s + N_T <= n_in; ++s) {
        bool ok = true;
        for (int j = 0; j < N_T; ++j)
            if (in_sizes[s + j] != EXP_SZ[j]) { ok = false; break; }
        if (ok) { o = s; break; }
    }
    if (o < 0) return;

    float* ws = (float*)d_ws;
    const long long PFN   = 270336;
    const long long C1o   = PFN;                 // 8388608 floats (33.5 MB)
    const long long C2o   = C1o + 8388608;       // 8388608 floats
    const long long C3o   = C2o + 8388608;       // 4194304 floats (16.8 MB)
    const long long Po    = C3o + 4194304;       // 8388608 floats
    const long long Qo    = Po  + 8388608;       // 8388608 floats
    const long long STo   = Qo  + 8388608;
    const long long FLo   = STo + 1024;
    const long long ZPo   = FLo + 64;
    const long long WBo   = ZPo + 16;
    const long long WBN   = 7628800;
    const size_t NEED = (size_t)WBo * 4 + WBN * 2 + 256;
    if (ws_size < NEED) return;

    float* PF = ws;
    unsigned short* C1 = (unsigned short*)(ws + C1o);
    unsigned short* C2 = (unsigned short*)(ws + C2o);
    unsigned short* C3 = (unsigned short*)(ws + C3o);
    unsigned short* P  = (unsigned short*)(ws + Po);
    unsigned short* Q  = (unsigned short*)(ws + Qo);
    float* ST = ws + STo;
    int* FLAGS = (int*)(ws + FLo);
    float* ZP = ws + ZPo;
    unsigned short* WB = (unsigned short*)(ws + WBo);
    // decoder aliases (liveness-planned):
    unsigned short* X3 = C3;   // u3b out (4,64,64,256), C3 skip dead after u3a
    unsigned short* U2 = P;    // stage-2 upsample (4,128,128,256) = 33.5 MB
    unsigned short* H2 = C2;   // u2b out (4,128,128,128), C2 skip dead
    unsigned short* U1 = P;    // stage-1 upsample (4,256,256,128) = 67 MB = P∪Q
    unsigned short* X1 = C3;   // u1a out (4,256,256,32), X3 dead after up2
    unsigned short* O1 = P;    // u1b out (4,256,256,32), U1 dead after u1a

    Tab tab;
    long long foff = 0, woff = 0;
    int nbc = 0;
    const float* fp[N_T];
    const unsigned short* wbp[N_T];
    for (int i = 0; i < N_T; ++i) {
        tab.src[i] = d_in[o + i];
        tab.n[i]   = in_sizes[o + i];
        tab.isw[i] = ISW[i];
        tab.cin[i] = CIN[i];
        tab.kk[i]  = KKA[i];
        tab.bs[i]  = nbc;
        nbc += (in_sizes[o + i] + 255) / 256;
        long long D1 = ISW[i] ? (long long)CIN[i] * KKA[i] : 1;
        long long D2 = ISW[i] ? (long long)KKA[i] : 1;
        tab.mckk[i] = ((1ULL << 39) + D1 - 1) / (unsigned long long)D1;
        tab.mkk[i]  = ((1ULL << 39) + D2 - 1) / (unsigned long long)D2;
        if (ISW[i]) { tab.dstoff[i] = woff; wbp[i] = WB + woff; fp[i] = nullptr; woff += tab.n[i]; }
        else        { tab.dstoff[i] = foff; fp[i] = PF + foff; wbp[i] = nullptr; foff += tab.n[i]; }
    }
    if (foff > PFN || woff > WBN) return;

    const float* xf  = fp[0];  const float* wf = fp[1];
    const unsigned short* d1w = wbp[2];  const float* d1b = fp[3];
    const unsigned short* w2a = wbp[4];  const float* b2a = fp[5];
    const unsigned short* w2b = wbp[6];  const float* b2b = fp[7];
    const unsigned short* w3a = wbp[8];  const float* b3a = fp[9];
    const unsigned short* w3b = wbp[10]; const float* b3b = fp[11];
    const unsigned short* w4a = wbp[12]; const float* b4a = fp[13];
    const unsigned short* w4b = wbp[14]; const float* b4b = fp[15];
    const float* g4 = fp[16], *be4 = fp[17];
    const unsigned short* u3aw = wbp[18]; const float* ub3a = fp[19];
    const unsigned short* u3bw = wbp[20]; const float* ub3b = fp[21];
    const unsigned short* u2aw = wbp[22]; const float* ub2a = fp[23];
    const unsigned short* u2bw = wbp[24]; const float* ub2b = fp[25];
    const unsigned short* u1aw = wbp[26]; const float* ub1a = fp[27];
    const unsigned short* u1bw = wbp[28]; const float* ub1b = fp[29];
    const float* wl = fp[30], *bl = fp[31];
    float* outp = (float*)d_out;

    dim3 blk(256);
    long long n;

    k_detect<<<N_T, blk, 0, stream>>>(tab, FLAGS);
    k_flag_final<<<1, 64, 0, stream>>>(tab, FLAGS, 0, ZP);
    k_convert<<<nbc, blk, 0, stream>>>(tab, PF, WB, FLAGS);

    // ---- encoder (NHWC bf16 feature maps) ----
    k_dynconv_mish<<<dim3(nblk(255 * 255), 4), blk, 0, stream>>>(xf, wf, P);
    // d1: k=4 pad=2, P (4,255,255,32) -> C1 (4,256,256,32)
    k_conv2<4, 4, 1, 2><<<dim3(4 * 16 * 16, 1), blk, 0, stream>>>(
        P, 32, nullptr, 0, d1w, d1b, C1, 255, 255, 256, 256, 32, ZP);
    n = 4ll * 128 * 128 * 32 / 8;
    k_maxpool<<<nblk(n), blk, 0, stream>>>(C1, Q, 8, 5, (int)n);
    // c2a: 32->128 @128^2 ; 1024 blocks
    k_conv2<3, 2, 2, 2><<<dim3(4 * 8 * 16, 2), blk, 0, stream>>>(
        Q, 32, nullptr, 0, w2a, b2a, P, 128, 128, 128, 128, 128, ZP);
    k_conv2<3, 2, 2, 2><<<dim3(4 * 8 * 16, 2), blk, 0, stream>>>(
        P, 128, nullptr, 0, w2b, b2b, C2, 128, 128, 128, 128, 128, ZP);
    n = 4ll * 64 * 64 * 128 / 8;
    k_maxpool<<<nblk(n), blk, 0, stream>>>(C2, Q, 7, 7, (int)n);
    // c3a: 128->256 @64^2 ; 1024 blocks
    k_conv2<3, 2, 2, 1><<<dim3(4 * 4 * 8, 8), blk, 0, stream>>>(
        Q, 128, nullptr, 0, w3a, b3a, P, 64, 64, 64, 64, 256, ZP);
    k_conv2<3, 2, 2, 1><<<dim3(4 * 4 * 8, 8), blk, 0, stream>>>(
        P, 256, nullptr, 0, w3b, b3b, C3, 64, 64, 64, 64, 256, ZP);
    n = 4ll * 32 * 32 * 256 / 8;
    k_maxpool<<<nblk(n), blk, 0, stream>>>(C3, Q, 6, 8, (int)n);
    // c4a: 256->512 @32^2 ; 512 blocks
    k_conv2<3, 2, 2, 1><<<dim3(4 * 2 * 4, 16), blk, 0, stream>>>(
        Q, 256, nullptr, 0, w4a, b4a, P, 32, 32, 32, 32, 512, ZP);
    k_conv2<3, 2, 2, 1><<<dim3(4 * 2 * 4, 16), blk, 0, stream>>>(
        P, 512, nullptr, 0, w4b, b4b, Q, 32, 32, 32, 32, 512, ZP);
    n = 4ll * 32 * 32 * 512 / 8;
    k_bn_reduce<<<512, blk, 0, stream>>>(Q, ST);
    k_bn_apply<<<nblk(n), blk, 0, stream>>>(Q, ST, g4, be4, (int)n);

    // ---- decoder ----
    // stage 3: up2 Q (4,32,32,512) -> P (4,64,64,512)
    n = 4ll * 64 * 64 * 512 / 8;
    k_up2<<<nblk(n), blk, 0, stream>>>(Q, P, 5, 9, (int)n);
    // u3a: [P:512 | C3:256] -> Q (4,64,64,256) ; 1024 blocks
    k_conv2<3, 2, 2, 1><<<dim3(4 * 4 * 8, 8), blk, 0, stream>>>(
        P, 512, C3, 256, u3aw, ub3a, Q, 64, 64, 64, 64, 256, ZP);
    // u3b: Q -> X3 (C3 region) ; 1024 blocks
    k_conv2<3, 2, 2, 1><<<dim3(4 * 4 * 8, 8), blk, 0, stream>>>(
        Q, 256, nullptr, 0, u3bw, ub3b, X3, 64, 64, 64, 64, 256, ZP);

    // stage 2 (batched): up2 X3 (4,64,64,256) -> U2 (=P region, 4,128,128,256)
    n = 4ll * 128 * 128 * 256 / 8;
    k_up2<<<nblk(n), blk, 0, stream>>>(X3, U2, 6, 8, (int)n);
    // u2a: [U2:256 | C2:128] -> Q (4,128,128,128) ; 1024 blocks
    k_conv2<3, 2, 2, 2><<<dim3(4 * 8 * 16, 2), blk, 0, stream>>>(
        U2, 256, C2, 128, u2aw, ub2a, Q, 128, 128, 128, 128, 128, ZP);
    // u2b: Q -> H2 (C2 region) ; 1024 blocks
    k_conv2<3, 2, 2, 2><<<dim3(4 * 8 * 16, 2), blk, 0, stream>>>(
        Q, 128, nullptr, 0, u2bw, ub2b, H2, 128, 128, 128, 128, 128, ZP);

    // stage 1 (batched): up2 H2 (4,128,128,128) -> U1 (=P∪Q, 4,256,256,128)
    n = 4ll * 256 * 256 * 128 / 8;
    k_up2<<<nblk(n), blk, 0, stream>>>(H2, U1, 7, 7, (int)n);
    // u1a: [U1:128 | C1:32] -> X1 (C3 region, 4,256,256,32) ; 1024 blocks
    k_conv2<3, 4, 1, 2><<<dim3(4 * 16 * 16, 1), blk, 0, stream>>>(
        U1, 128, C1, 32, u1aw, ub1a, X1, 256, 256, 256, 256, 32, ZP);
    // u1b: X1 -> O1 (P region)
    k_conv2<3, 4, 1, 2><<<dim3(4 * 16 * 16, 1), blk, 0, stream>>>(
        X1, 32, nullptr, 0, u1bw, ub1b, O1, 256, 256, 256, 256, 32, ZP);

    // final 1x1 -> f32 out (NCHW == NHW for 1 channel)
    n = 4ll * 256 * 256;
    k_final1x1<<<nblk(n), blk, 0, stream>>>(O1, wl, bl, outp);
}

// Round 12
// 645.233 us; speedup vs baseline: 1.0464x; 1.0464x over previous
//
#include <hip/hip_runtime.h>
#include <hip/hip_bf16.h>
#include <math.h>

#define DEV static __device__ __forceinline__

typedef __attribute__((ext_vector_type(8))) short short8;
typedef __attribute__((ext_vector_type(4))) float floatx4;

DEV float bf2f(const __hip_bfloat16 v) { return __bfloat162float(v); }
DEV float bfu2f(unsigned short u) { return __uint_as_float((unsigned)u << 16); }

DEV unsigned short f2bf(float v) {   // RNE f32 -> bf16 bits
    unsigned int b = __float_as_uint(v);
    unsigned int r = (b + 0x7FFFu + ((b >> 16) & 1u)) >> 16;
    return (unsigned short)r;
}

DEV float mishf(float x) {
    float sp = fmaxf(x, 0.0f) + __logf(1.0f + __expf(-fabsf(x)));
    float t = __expf(-2.0f * sp);
    return __fdividef(x * (1.0f - t), 1.0f + t);
}

// wait until at most N VMEM loads outstanding (gfx9 encoding; lgkm/exp ignored)
template<int N> DEV void s_wait_vm() {
    constexpr unsigned e = (unsigned)(N & 15) | (((unsigned)N >> 4) << 14)
                         | (7u << 4) | (15u << 8);
    __builtin_amdgcn_s_waitcnt(e);
}

#define N_T 32
struct Tab {
    const void* src[N_T];
    long long   dstoff[N_T];
    int         n[N_T];
    int         isw[N_T];   // 1 = conv weight -> bf16 WB region (frag layout)
    int         cin[N_T];
    int         kk[N_T];
    int         bs[N_T];                 // block-prefix (static sizes)
    unsigned long long mckk[N_T];        // magic: ceil(2^39 / (cin*kk))
    unsigned long long mkk[N_T];         // magic: ceil(2^39 / kk)
};

// ---------------- per-array dtype detection ----------------
__global__ __launch_bounds__(256) void k_detect(Tab t, int* __restrict__ flags) {
    int i = blockIdx.x;
    int n = t.n[i];
    int m = n < 16384 ? n : 16384;
    const unsigned short* p = (const unsigned short*)t.src[i];
    __shared__ int sInf, sExt, sZero;
    if (threadIdx.x == 0) { sInf = 0; sExt = 0; sZero = 0; }
    __syncthreads();
    int cInf = 0, cExt = 0, cZero = 0;
    for (int j = threadIdx.x; j < m; j += 256) {
        unsigned short h = p[j];
        if ((h & 0x7F80) == 0x7F80) cInf++;
        if ((j & 1) == 0) {
            if (h == 0) cZero++;
            else { int e = (h >> 7) & 0xFF; if (e < 56 || e > 184) cExt++; }
        }
    }
    if (cInf)  atomicAdd(&sInf, cInf);
    if (cExt)  atomicAdd(&sExt, cExt);
    if (cZero) atomicAdd(&sZero, cZero);
    __syncthreads();
    if (threadIdx.x == 0) {
        int nEven = (m + 1) >> 1;
        flags[i] = (sInf > 0 || sExt > 0 || (nEven > 0 && sZero == nEven)) ? 2 : 0;
    }
}

__global__ void k_flag_final(Tab t, int* __restrict__ flags, int xi,
                             float* __restrict__ zp) {
    if (blockIdx.x == 0 && threadIdx.x < 16) zp[threadIdx.x] = 0.0f;
    if (threadIdx.x == 0 && blockIdx.x == 0) {
        int xf = (flags[xi] == 2) ? 1 : 0;
        for (int i = 0; i < N_T; ++i) {
            int f;
            if (flags[i] == 2)       f = 1;
            else if (t.n[i] >= 256)  f = 0;
            else                     f = xf;
            flags[i] = f;            // 1 = f32, 0 = bf16
        }
    }
}

// convert: conv weights -> bf16 WB in MFMA-fragment order. Block->entry via
// static block-prefix (scalar scan); divisions via host-precomputed magic
// multiply ((j*M)>>39, exact for j<2^22, D<=8192).
__global__ __launch_bounds__(256) void k_convert(
        Tab t, float* __restrict__ pf, unsigned short* __restrict__ wb,
        const int* __restrict__ flags) {
    int bx = blockIdx.x;
    int i = 0;
    #pragma unroll 1
    while (i + 1 < N_T && bx >= t.bs[i + 1]) ++i;
    int j = (bx - t.bs[i]) * 256 + threadIdx.x;
    if (j >= t.n[i]) return;
    float v = flags[i] ? ((const float*)t.src[i])[j]
                       : bf2f(((const __hip_bfloat16*)t.src[i])[j]);
    if (t.isw[i]) {
        int kk = t.kk[i], cin = t.cin[i];
        int ckk = cin * kk;
        unsigned co = (unsigned)(((unsigned long long)(unsigned)j
                                  * t.mckk[i]) >> 39);
        int rem = j - (int)co * ckk;
        unsigned ci = (unsigned)(((unsigned long long)(unsigned)rem
                                  * t.mkk[i]) >> 39);
        int tt = rem - (int)ci * kk;
        int cb = (int)co >> 4, m = (int)co & 15;
        int ch = (int)ci >> 5, q = ((int)ci >> 3) & 3, jj = (int)ci & 7;
        int nc = cin >> 5;
        size_t dst = (((size_t)(cb * kk + tt) * nc + ch) << 9)
                   + (size_t)((q << 4) + m) * 8 + jj;
        wb[t.dstoff[i] + dst] = f2bf(v);
    } else {
        pf[t.dstoff[i] + j] = v;
    }
}

// ------- dynamic per-sample conv (k=4, pad=1) + mish -> NHWC bf16 -----------
__global__ __launch_bounds__(256) void k_dynconv_mish(
        const float* __restrict__ x, const float* __restrict__ w,
        unsigned short* __restrict__ out) {
    const int HO = 255, WO = 255, H = 256, W = 256;
    int p = blockIdx.x * 256 + threadIdx.x;
    if (p >= HO * WO) return;
    int b = blockIdx.y;
    int yo = p / WO, xo = p - yo * WO;
    const float* xp = x + b * H * W;

    float xv[16];
    #pragma unroll
    for (int ky = 0; ky < 4; ++ky) {
        int iy = yo + ky - 1;
        bool yok = (unsigned)iy < (unsigned)H;
        #pragma unroll
        for (int kx = 0; kx < 4; ++kx) {
            int ix = xo + kx - 1;
            xv[ky * 4 + kx] = (yok && (unsigned)ix < (unsigned)W)
                              ? xp[iy * W + ix] : 0.0f;
        }
    }

    const float* wb = w + (b << 9);
    unsigned int ow[16];
    #pragma unroll
    for (int c2 = 0; c2 < 16; ++c2) {
        const float* w0 = wb + (c2 << 5);
        const float* w1 = w0 + 16;
        float a0 = 0.f, a1 = 0.f;
        #pragma unroll
        for (int k = 0; k < 16; ++k) {
            a0 = fmaf(xv[k], w0[k], a0);
            a1 = fmaf(xv[k], w1[k], a1);
        }
        ow[c2] = (unsigned)f2bf(mishf(a0)) | ((unsigned)f2bf(mishf(a1)) << 16);
    }

    unsigned short* op = out + ((size_t)(b * HO * WO) + p) * 32;
    uint4 v;
    v.x = ow[0];  v.y = ow[1];  v.z = ow[2];  v.w = ow[3];
    *(uint4*)(op +  0) = v;
    v.x = ow[4];  v.y = ow[5];  v.z = ow[6];  v.w = ow[7];
    *(uint4*)(op +  8) = v;
    v.x = ow[8];  v.y = ow[9];  v.z = ow[10]; v.w = ow[11];
    *(uint4*)(op + 16) = v;
    v.x = ow[12]; v.y = ow[13]; v.z = ow[14]; v.w = ow[15];
    *(uint4*)(op + 24) = v;
}

// ============ halo-staged NHWC direct-conv MFMA (bf16 in/out, f32 acc) =======
// Block = 256 threads = 4 waves arranged WPX (px) x WCO (co).
// T4 counted-vmcnt pipeline per 32-ci chunk (see R9); KS==3 row-major B reads
// (18 ds_read instead of 36); T2 LDS XOR-swizzle (R11, conflicts 3.5M -> 0).
template<int KS, int WPX, int WCO, int CO_FR>
__global__ __launch_bounds__(256) void k_conv2(
        const unsigned short* __restrict__ s0, int C0,
        const unsigned short* __restrict__ s1, int C1,
        const unsigned short* __restrict__ wgt,
        const float* __restrict__ bias,
        unsigned short* __restrict__ out,
        int Hin, int Win, int Hout, int Wout, int Co,
        const float* __restrict__ zpad) {
    constexpr int PAD = KS - 2;               // 3->1, 4->2
    constexpr int KK = KS * KS;
    constexpr int TY = WPX * 4;
    constexpr int HWd = 16 + KS - 1;
    constexpr int HHd = TY + KS - 1;
    constexpr int NLOC = HWd * HHd;
    constexpr int NLD = NLOC * 4;             // 16B-loads per chunk
    constexpr int NPASS = (NLD + 255) / 256;
    constexpr int HALF = NPASS * 2048;        // shorts per buffer half
    constexpr int NAV = (KS == 3) ? KK * CO_FR : 0;
    static_assert(2 * HALF * 2 <= 65536, "LDS overflow");
    static_assert(WPX * WCO == 4, "4 waves");
    static_assert(NAV + NPASS <= 63, "vmcnt range");
    __shared__ __align__(16) unsigned short lds[2 * HALF];

    const int tid = threadIdx.x, lane = tid & 63, wv = tid >> 6;
    const int wr = wv / WCO, wc = wv % WCO;
    const int xn = lane & 15, qd = lane >> 4;
    const int C = C0 + C1, NC = C >> 5;
    const int NC0 = C0 >> 5;

    const int txc = Wout >> 4, tyc = Hout / TY;
    const int tpb = txc * tyc;
    const int b = blockIdx.x / tpb;
    int rem = blockIdx.x - b * tpb;
    const int tyi = rem / txc, txi = rem - tyi * txc;
    const int y0 = tyi * TY, x0 = txi << 4;
    const int cobase = blockIdx.y * (WCO * CO_FR * 16);
    const int cob16_0 = (cobase >> 4) + wc * CO_FR;

    const unsigned short* sb0 = s0 + (size_t)b * Hin * Win * C0;
    const unsigned short* sb1 = s1 ? s1 + (size_t)b * Hin * Win * C1 : s0;

    // swizzled LDS byte->short offset for pixel-slot t, ci-group qd
    auto swz = [&](int t) { return t * 32 + (((qd ^ (t >> 1)) & 3) << 3); };

    floatx4 acc[4][CO_FR];
    #pragma unroll
    for (int p = 0; p < 4; ++p)
        #pragma unroll
        for (int q = 0; q < CO_FR; ++q)
            acc[p][q] = (floatx4){0.f, 0.f, 0.f, 0.f};

    // --- hoisted staging state (chunk-independent parts) ---
    int srow[NPASS];
    int sinc[NPASS];                          // 32 if lane stages real data
    int c8s[NPASS];                           // inverse-swizzled ci-group
    #pragma unroll
    for (int p_ = 0; p_ < NPASS; ++p_) {
        int i_ = p_ * 256 + tid;
        int loc = i_ >> 2;
        int hy = loc / HWd, hx = loc - hy * HWd;
        int iy = y0 + hy - PAD, ix = x0 + hx - PAD;
        bool ok = (i_ < NLD) && ((unsigned)iy < (unsigned)Hin)
                             && ((unsigned)ix < (unsigned)Win);
        srow[p_] = iy * Win + ix;
        sinc[p_] = ok ? 32 : 0;
        c8s[p_] = (((i_ & 3) ^ ((i_ >> 3) & 3))) << 3;
    }
    const unsigned short* sptr[NPASS];
    auto initp = [&](const unsigned short* srcp, int Cs) {
        #pragma unroll
        for (int p_ = 0; p_ < NPASS; ++p_)
            sptr[p_] = sinc[p_] ? srcp + (size_t)srow[p_] * Cs + c8s[p_]
                                : (const unsigned short*)zpad;
    };
    int scnt = 0;
    auto stage_next = [&](int h_) {
        if (s1 && scnt == NC0) initp(sb1, C1);
        #pragma unroll
        for (int p_ = 0; p_ < NPASS; ++p_) {
            __builtin_amdgcn_global_load_lds(
                (const unsigned int*)sptr[p_],
                (unsigned int*)&lds[h_ * HALF + (p_ * 256 + wv * 64) * 8],
                16, 0, 0);
            sptr[p_] += sinc[p_];
        }
        ++scnt;
    };

    initp(sb0, C0);
    stage_next(0);
    for (int ci_ = 0; ci_ < NC; ++ci_) {
        const int h = ci_ & 1;
        const size_t wof = ((size_t)cob16_0 * KK * NC + ci_) * 512 + lane * 8;
        // 1) A-fragment prefetch into regs, issued BEFORE staging so the
        //    compiler's av-consume waits exclude the fresh staging loads.
        short8 avr[KK][CO_FR];
        if constexpr (KS == 3) {
            #pragma unroll
            for (int tap = 0; tap < KK; ++tap)
                #pragma unroll
                for (int q = 0; q < CO_FR; ++q)
                    avr[tap][q] = *(const short8*)(wgt + wof
                                    + (size_t)(q * KK + tap) * NC * 512);
            __builtin_amdgcn_sched_barrier(0);
        }
        // 2) issue next-chunk staging (stays in flight across the barrier)
        if (ci_ + 1 < NC) stage_next(h ^ 1);
        __builtin_amdgcn_sched_barrier(0);
        // 3) counted wait: everything older than {avr, next staging} retired
        //    => this chunk's staging landed (in-order vmcnt retirement)
        if (ci_ + 1 < NC) s_wait_vm<NAV + NPASS>();
        else              s_wait_vm<NAV>();
        __builtin_amdgcn_s_barrier();
        __builtin_amdgcn_sched_barrier(0);
        // 4) compute this chunk from LDS + avr
        const unsigned short* base = &lds[h * HALF];
        if constexpr (KS == 3) {
            // row-major: each of the 6 halo rows read once (3 dx frags)
            #pragma unroll
            for (int r = 0; r < 6; ++r) {
                short8 bv[3];
                #pragma unroll
                for (int dx = 0; dx < 3; ++dx) {
                    int t = (4 * wr + r) * HWd + xn + dx;
                    bv[dx] = *(const short8*)&base[swz(t)];
                }
                #pragma unroll
                for (int dy = 0; dy < 3; ++dy) {
                    const int p = r - dy;
                    if (p >= 0 && p < 4) {
                        #pragma unroll
                        for (int dx = 0; dx < 3; ++dx) {
                            const int tap = dy * 3 + dx;
                            #pragma unroll
                            for (int q = 0; q < CO_FR; ++q)
                                acc[p][q] =
                                    __builtin_amdgcn_mfma_f32_16x16x32_bf16(
                                        avr[tap][q], bv[dx], acc[p][q],
                                        0, 0, 0);
                        }
                    }
                }
            }
        } else {
            #pragma unroll
            for (int dy = 0; dy < KS; ++dy) {
                #pragma unroll
                for (int dx = 0; dx < KS; ++dx) {
                    const int tap = dy * KS + dx;
                    short8 av[CO_FR];
                    #pragma unroll
                    for (int q = 0; q < CO_FR; ++q)
                        av[q] = *(const short8*)(wgt + wof
                                  + (size_t)(q * KK + tap) * NC * 512);
                    #pragma unroll
                    for (int p = 0; p < 4; ++p) {
                        int t = (4 * wr + p + dy) * HWd + xn + dx;
                        short8 bv = *(const short8*)&base[swz(t)];
                        #pragma unroll
                        for (int q = 0; q < CO_FR; ++q)
                            acc[p][q] = __builtin_amdgcn_mfma_f32_16x16x32_bf16(
                                av[q], bv, acc[p][q], 0, 0, 0);
                    }
                }
            }
        }
        __builtin_amdgcn_sched_barrier(0);
        __builtin_amdgcn_s_barrier();     // WAR: all waves done reading buf[h]
        __builtin_amdgcn_sched_barrier(0);
    }

    // epilogue: bias + mish -> NHWC bf16, 4 consecutive co per lane
    #pragma unroll
    for (int p = 0; p < 4; ++p) {
        const int y = y0 + 4 * wr + p;
        unsigned short* ob = out + (((size_t)b * Hout + y) * Wout + x0 + xn) * Co;
        #pragma unroll
        for (int q = 0; q < CO_FR; ++q) {
            const int co = cobase + (wc * CO_FR + q) * 16 + qd * 4;
            ushort4 o;
            o.x = f2bf(mishf(acc[p][q][0] + bias[co + 0]));
            o.y = f2bf(mishf(acc[p][q][1] + bias[co + 1]));
            o.z = f2bf(mishf(acc[p][q][2] + bias[co + 2]));
            o.w = f2bf(mishf(acc[p][q][3] + bias[co + 3]));
            *(ushort4*)(ob + co) = o;
        }
    }
}

// ------- 2x2 maxpool stride 2 (NHWC bf16, square pow2), 8 ch/thread --------
__global__ __launch_bounds__(256) void k_maxpool(
        const unsigned short* __restrict__ in, unsigned short* __restrict__ out,
        int lgWin, int lgC, int total8) {
    int idx = blockIdx.x * 256 + threadIdx.x;
    if (idx >= total8) return;
    int Wo = 1 << (lgWin - 1);
    int vc = idx & ((1 << (lgC - 3)) - 1); int t = idx >> (lgC - 3);
    int xo = t & (Wo - 1); t >>= (lgWin - 1);
    int yo = t & (Wo - 1); int b = t >> (lgWin - 1);
    size_t base = (((((size_t)(b << lgWin) + 2 * yo) << lgWin) + 2 * xo) << lgC)
                + ((size_t)vc << 3);
    size_t dc = (size_t)1 << lgC, dr = (size_t)1 << (lgWin + lgC);
    short8 v0 = *(const short8*)&in[base];
    short8 v1 = *(const short8*)&in[base + dc];
    short8 v2 = *(const short8*)&in[base + dr];
    short8 v3 = *(const short8*)&in[base + dr + dc];
    short8 o;
    #pragma unroll
    for (int j = 0; j < 8; ++j) {
        float m = fmaxf(fmaxf(bfu2f((unsigned short)v0[j]),
                              bfu2f((unsigned short)v1[j])),
                        fmaxf(bfu2f((unsigned short)v2[j]),
                              bfu2f((unsigned short)v3[j])));
        o[j] = (short)f2bf(m);
    }
    *(short8*)&out[(size_t)idx * 8] = o;
}

// ---------------- batchnorm (batch stats) on NHWC (4,32,32,512) bf16 --------
__global__ __launch_bounds__(256) void k_bn_reduce(
        const unsigned short* __restrict__ in, float* __restrict__ stats) {
    __shared__ float ls[4], ls2[4];
    int c = blockIdx.x;
    int tid = threadIdx.x;
    float s = 0.f, s2 = 0.f;
    for (int i = tid; i < 4096; i += 256) {
        float v = bfu2f(in[(size_t)i * 512 + c]);
        s += v; s2 += v * v;
    }
    #pragma unroll
    for (int off = 32; off; off >>= 1) {
        s  += __shfl_down(s, off, 64);
        s2 += __shfl_down(s2, off, 64);
    }
    if ((tid & 63) == 0) { ls[tid >> 6] = s; ls2[tid >> 6] = s2; }
    __syncthreads();
    if (tid == 0) {
        s  = ls[0] + ls[1] + ls[2] + ls[3];
        s2 = ls2[0] + ls2[1] + ls2[2] + ls2[3];
        float mean = s * (1.f / 4096.f);
        float var  = fmaxf(s2 * (1.f / 4096.f) - mean * mean, 0.f);
        stats[c]       = mean;
        stats[512 + c] = rsqrtf(var + 1e-5f);
    }
}

// bn apply, 8 ch/thread (short8)
__global__ __launch_bounds__(256) void k_bn_apply(
        unsigned short* __restrict__ data, const float* __restrict__ stats,
        const float* __restrict__ g, const float* __restrict__ be, int total8) {
    int idx = blockIdx.x * 256 + threadIdx.x;
    if (idx >= total8) return;
    int c0 = (idx & 63) << 3;
    short8 v = *(const short8*)&data[(size_t)idx * 8];
    short8 o;
    #pragma unroll
    for (int j = 0; j < 8; ++j) {
        int c = c0 + j;
        float x = bfu2f((unsigned short)v[j]);
        o[j] = (short)f2bf(g[c] * (x - stats[c]) * stats[512 + c] + be[c]);
    }
    *(short8*)&data[(size_t)idx * 8] = o;
}

// ---- bilinear x2 upsample, align_corners=True, NHWC bf16, 8 ch/thread ------
__global__ __launch_bounds__(256) void k_up2(
        const unsigned short* __restrict__ in, unsigned short* __restrict__ out,
        int lgW, int lgC, int total8) {
    int idx = blockIdx.x * 256 + threadIdx.x;
    if (idx >= total8) return;
    int H = 1 << lgW;
    int vc = idx & ((1 << (lgC - 3)) - 1); int t = idx >> (lgC - 3);
    int xo = t & (2 * H - 1); t >>= (lgW + 1);
    int yo = t & (2 * H - 1); int b = t >> (lgW + 1);
    float sc = (float)(H - 1) / (float)(2 * H - 1);
    float sy = yo * sc, sx = xo * sc;
    int y0 = (int)sy; int y1 = min(y0 + 1, H - 1); float fy = sy - (float)y0;
    int x0 = (int)sx; int x1 = min(x0 + 1, H - 1); float fx = sx - (float)x0;
    size_t bb = (size_t)b << (2 * lgW);
    size_t c = (size_t)vc << 3;
    size_t i00 = (((bb + ((size_t)y0 << lgW) + x0)) << lgC) + c;
    size_t i01 = (((bb + ((size_t)y0 << lgW) + x1)) << lgC) + c;
    size_t i10 = (((bb + ((size_t)y1 << lgW) + x0)) << lgC) + c;
    size_t i11 = (((bb + ((size_t)y1 << lgW) + x1)) << lgC) + c;
    short8 a00 = *(const short8*)&in[i00];
    short8 a01 = *(const short8*)&in[i01];
    short8 a10 = *(const short8*)&in[i10];
    short8 a11 = *(const short8*)&in[i11];
    short8 o;
    #pragma unroll
    for (int j = 0; j < 8; ++j) {
        float a  = bfu2f((unsigned short)a00[j]) * (1.f - fx)
                 + bfu2f((unsigned short)a01[j]) * fx;
        float b2 = bfu2f((unsigned short)a10[j]) * (1.f - fx)
                 + bfu2f((unsigned short)a11[j]) * fx;
        o[j] = (short)f2bf(a * (1.f - fy) + b2 * fy);
    }
    *(short8*)&out[(size_t)idx * 8] = o;
}

// ---------------- final 1x1 conv, NHWC(4,256,256,32) bf16 -> f32 ------------
__global__ __launch_bounds__(256) void k_final1x1(
        const unsigned short* __restrict__ in, const float* __restrict__ wl,
        const float* __restrict__ bl, float* __restrict__ out) {
    int idx = blockIdx.x * 256 + threadIdx.x;
    if (idx >= 4 * 256 * 256) return;
    const unsigned short* p = in + (size_t)idx * 32;
    short8 r0 = *(const short8*)&p[0];
    short8 r1 = *(const short8*)&p[8];
    short8 r2 = *(const short8*)&p[16];
    short8 r3 = *(const short8*)&p[24];
    float acc = bl[0];
    #pragma unroll
    for (int j = 0; j < 8; ++j) {
        acc = fmaf(bfu2f((unsigned short)r0[j]), wl[j],      acc);
        acc = fmaf(bfu2f((unsigned short)r1[j]), wl[j + 8],  acc);
        acc = fmaf(bfu2f((unsigned short)r2[j]), wl[j + 16], acc);
        acc = fmaf(bfu2f((unsigned short)r3[j]), wl[j + 24], acc);
    }
    out[idx] = acc;
}

static inline int nblk(long long n) { return (int)((n + 255) / 256); }

extern "C" void kernel_launch(void* const* d_in, const int* in_sizes, int n_in,
                              void* d_out, int out_size, void* d_ws, size_t ws_size,
                              hipStream_t stream) {
    static const int EXP_SZ[N_T] = {
        262144, 2048, 16384, 32, 36864, 128, 147456, 128,
        294912, 256, 589824, 256, 1179648, 512, 2359296, 512,
        512, 512, 1769472, 256, 589824, 256, 442368, 128,
        147456, 128, 46080, 32, 9216, 32, 32, 1 };
    static const int ISW[N_T] = {
        0,0,1,0, 1,0,1,0, 1,0,1,0, 1,0,1,0,
        0,0, 1,0,1,0, 1,0,1,0, 1,0,1,0, 0,0 };
    static const int CIN[N_T] = {
        0,0,32,0, 32,0,128,0, 128,0,256,0, 256,0,512,0,
        0,0, 768,0,256,0, 384,0,128,0, 160,0,32,0, 0,0 };
    static const int KKA[N_T] = {
        0,0,16,0, 9,0,9,0, 9,0,9,0, 9,0,9,0,
        0,0, 9,0,9,0, 9,0,9,0, 9,0,9,0, 0,0 };
    int o = -1;
    for (int s = 0; s + N_T <= n_in; ++s) {
        bool ok = true;
        for (int j = 0; j < N_T; ++j)
            if (in_sizes[s + j] != EXP_SZ[j]) { ok = false; break; }
        if (ok) { o = s; break; }
    }
    if (o < 0) return;

    float* ws = (float*)d_ws;
    const long long PFN   = 270336;
    const long long C1o   = PFN;                 // 8388608 floats (33.5 MB)
    const long long C2o   = C1o + 8388608;       // 8388608 floats
    const long long C3o   = C2o + 8388608;       // 4194304 floats (16.8 MB)
    const long long Po    = C3o + 4194304;       // 8388608 floats
    const long long Qo    = Po  + 8388608;       // 8388608 floats
    const long long STo   = Qo  + 8388608;
    const long long FLo   = STo + 1024;
    const long long ZPo   = FLo + 64;
    const long long WBo   = ZPo + 16;
    const long long WBN   = 7628800;
    const size_t NEED = (size_t)WBo * 4 + WBN * 2 + 256;
    if (ws_size < NEED) return;

    float* PF = ws;
    unsigned short* C1 = (unsigned short*)(ws + C1o);
    unsigned short* C2 = (unsigned short*)(ws + C2o);
    unsigned short* C3 = (unsigned short*)(ws + C3o);
    unsigned short* P  = (unsigned short*)(ws + Po);
    unsigned short* Q  = (unsigned short*)(ws + Qo);
    float* ST = ws + STo;
    int* FLAGS = (int*)(ws + FLo);
    float* ZP = ws + ZPo;
    unsigned short* WB = (unsigned short*)(ws + WBo);
    // decoder aliases (liveness-planned):
    unsigned short* X3 = C3;   // u3b out (4,64,64,256), C3 skip dead after u3a
    unsigned short* U2 = P;    // stage-2 upsample (4,128,128,256) = 33.5 MB
    unsigned short* H2 = C2;   // u2b out (4,128,128,128), C2 skip dead
    unsigned short* U1 = P;    // stage-1 upsample (4,256,256,128) = 67 MB = P∪Q
    unsigned short* X1 = C3;   // u1a out (4,256,256,32), X3 dead after up2
    unsigned short* O1 = P;    // u1b out (4,256,256,32), U1 dead after u1a

    Tab tab;
    long long foff = 0, woff = 0;
    int nbc = 0;
    const float* fp[N_T];
    const unsigned short* wbp[N_T];
    for (int i = 0; i < N_T; ++i) {
        tab.src[i] = d_in[o + i];
        tab.n[i]   = in_sizes[o + i];
        tab.isw[i] = ISW[i];
        tab.cin[i] = CIN[i];
        tab.kk[i]  = KKA[i];
        tab.bs[i]  = nbc;
        nbc += (in_sizes[o + i] + 255) / 256;
        long long D1 = ISW[i] ? (long long)CIN[i] * KKA[i] : 1;
        long long D2 = ISW[i] ? (long long)KKA[i] : 1;
        tab.mckk[i] = ((1ULL << 39) + D1 - 1) / (unsigned long long)D1;
        tab.mkk[i]  = ((1ULL << 39) + D2 - 1) / (unsigned long long)D2;
        if (ISW[i]) { tab.dstoff[i] = woff; wbp[i] = WB + woff; fp[i] = nullptr; woff += tab.n[i]; }
        else        { tab.dstoff[i] = foff; fp[i] = PF + foff; wbp[i] = nullptr; foff += tab.n[i]; }
    }
    if (foff > PFN || woff > WBN) return;

    const float* xf  = fp[0];  const float* wf = fp[1];
    const unsigned short* d1w = wbp[2];  const float* d1b = fp[3];
    const unsigned short* w2a = wbp[4];  const float* b2a = fp[5];
    const unsigned short* w2b = wbp[6];  const float* b2b = fp[7];
    const unsigned short* w3a = wbp[8];  const float* b3a = fp[9];
    const unsigned short* w3b = wbp[10]; const float* b3b = fp[11];
    const unsigned short* w4a = wbp[12]; const float* b4a = fp[13];
    const unsigned short* w4b = wbp[14]; const float* b4b = fp[15];
    const float* g4 = fp[16], *be4 = fp[17];
    const unsigned short* u3aw = wbp[18]; const float* ub3a = fp[19];
    const unsigned short* u3bw = wbp[20]; const float* ub3b = fp[21];
    const unsigned short* u2aw = wbp[22]; const float* ub2a = fp[23];
    const unsigned short* u2bw = wbp[24]; const float* ub2b = fp[25];
    const unsigned short* u1aw = wbp[26]; const float* ub1a = fp[27];
    const unsigned short* u1bw = wbp[28]; const float* ub1b = fp[29];
    const float* wl = fp[30], *bl = fp[31];
    float* outp = (float*)d_out;

    dim3 blk(256);
    long long n;

    k_detect<<<N_T, blk, 0, stream>>>(tab, FLAGS);
    k_flag_final<<<1, 64, 0, stream>>>(tab, FLAGS, 0, ZP);
    k_convert<<<nbc, blk, 0, stream>>>(tab, PF, WB, FLAGS);

    // ---- encoder (NHWC bf16 feature maps) ----
    k_dynconv_mish<<<dim3(nblk(255 * 255), 4), blk, 0, stream>>>(xf, wf, P);
    // d1: k=4 pad=2, P (4,255,255,32) -> C1 (4,256,256,32)
    k_conv2<4, 4, 1, 2><<<dim3(4 * 16 * 16, 1), blk, 0, stream>>>(
        P, 32, nullptr, 0, d1w, d1b, C1, 255, 255, 256, 256, 32, ZP);
    n = 4ll * 128 * 128 * 32 / 8;
    k_maxpool<<<nblk(n), blk, 0, stream>>>(C1, Q, 8, 5, (int)n);
    // c2a: 32->128 @128^2 ; 1024 blocks
    k_conv2<3, 2, 2, 2><<<dim3(4 * 8 * 16, 2), blk, 0, stream>>>(
        Q, 32, nullptr, 0, w2a, b2a, P, 128, 128, 128, 128, 128, ZP);
    k_conv2<3, 2, 2, 2><<<dim3(4 * 8 * 16, 2), blk, 0, stream>>>(
        P, 128, nullptr, 0, w2b, b2b, C2, 128, 128, 128, 128, 128, ZP);
    n = 4ll * 64 * 64 * 128 / 8;
    k_maxpool<<<nblk(n), blk, 0, stream>>>(C2, Q, 7, 7, (int)n);
    // c3a: 128->256 @64^2 ; CO_FR=2, y=4 -> 512 blocks (CO_FR=2 > CO_FR=1,
    // R11 equal-FLOP evidence: u2a 65.6 vs u3a 71.5)
    k_conv2<3, 2, 2, 2><<<dim3(4 * 4 * 8, 4), blk, 0, stream>>>(
        Q, 128, nullptr, 0, w3a, b3a, P, 64, 64, 64, 64, 256, ZP);
    k_conv2<3, 2, 2, 2><<<dim3(4 * 4 * 8, 4), blk, 0, stream>>>(
        P, 256, nullptr, 0, w3b, b3b, C3, 64, 64, 64, 64, 256, ZP);
    n = 4ll * 32 * 32 * 256 / 8;
    k_maxpool<<<nblk(n), blk, 0, stream>>>(C3, Q, 6, 8, (int)n);
    // c4a: 256->512 @32^2 ; 512 blocks (CO_FR=1: CO_FR=2 would be 1 blk/CU)
    k_conv2<3, 2, 2, 1><<<dim3(4 * 2 * 4, 16), blk, 0, stream>>>(
        Q, 256, nullptr, 0, w4a, b4a, P, 32, 32, 32, 32, 512, ZP);
    k_conv2<3, 2, 2, 1><<<dim3(4 * 2 * 4, 16), blk, 0, stream>>>(
        P, 512, nullptr, 0, w4b, b4b, Q, 32, 32, 32, 32, 512, ZP);
    n = 4ll * 32 * 32 * 512 / 8;
    k_bn_reduce<<<512, blk, 0, stream>>>(Q, ST);
    k_bn_apply<<<nblk(n), blk, 0, stream>>>(Q, ST, g4, be4, (int)n);

    // ---- decoder ----
    // stage 3: up2 Q (4,32,32,512) -> P (4,64,64,512)
    n = 4ll * 64 * 64 * 512 / 8;
    k_up2<<<nblk(n), blk, 0, stream>>>(Q, P, 5, 9, (int)n);
    // u3a: [P:512 | C3:256] -> Q (4,64,64,256) ; CO_FR=2, y=4 -> 512 blocks
    k_conv2<3, 2, 2, 2><<<dim3(4 * 4 * 8, 4), blk, 0, stream>>>(
        P, 512, C3, 256, u3aw, ub3a, Q, 64, 64, 64, 64, 256, ZP);
    // u3b: Q -> X3 (C3 region) ; CO_FR=2, y=4
    k_conv2<3, 2, 2, 2><<<dim3(4 * 4 * 8, 4), blk, 0, stream>>>(
        Q, 256, nullptr, 0, u3bw, ub3b, X3, 64, 64, 64, 64, 256, ZP);

    // stage 2 (batched): up2 X3 (4,64,64,256) -> U2 (=P region, 4,128,128,256)
    n = 4ll * 128 * 128 * 256 / 8;
    k_up2<<<nblk(n), blk, 0, stream>>>(X3, U2, 6, 8, (int)n);
    // u2a: [U2:256 | C2:128] -> Q (4,128,128,128) ; 1024 blocks
    k_conv2<3, 2, 2, 2><<<dim3(4 * 8 * 16, 2), blk, 0, stream>>>(
        U2, 256, C2, 128, u2aw, ub2a, Q, 128, 128, 128, 128, 128, ZP);
    // u2b: Q -> H2 (C2 region) ; 1024 blocks
    k_conv2<3, 2, 2, 2><<<dim3(4 * 8 * 16, 2), blk, 0, stream>>>(
        Q, 128, nullptr, 0, u2bw, ub2b, H2, 128, 128, 128, 128, 128, ZP);

    // stage 1 (batched): up2 H2 (4,128,128,128) -> U1 (=P∪Q, 4,256,256,128)
    n = 4ll * 256 * 256 * 128 / 8;
    k_up2<<<nblk(n), blk, 0, stream>>>(H2, U1, 7, 7, (int)n);
    // u1a: [U1:128 | C1:32] -> X1 (C3 region, 4,256,256,32) ; 1024 blocks
    k_conv2<3, 4, 1, 2><<<dim3(4 * 16 * 16, 1), blk, 0, stream>>>(
        U1, 128, C1, 32, u1aw, ub1a, X1, 256, 256, 256, 256, 32, ZP);
    // u1b: X1 -> O1 (P region)
    k_conv2<3, 4, 1, 2><<<dim3(4 * 16 * 16, 1), blk, 0, stream>>>(
        X1, 32, nullptr, 0, u1bw, ub1b, O1, 256, 256, 256, 256, 32, ZP);

    // final 1x1 -> f32 out (NCHW == NHW for 1 channel)
    n = 4ll * 256 * 256;
    k_final1x1<<<nblk(n), blk, 0, stream>>>(O1, wl, bl, outp);
}